// Round 1
// baseline (330.218 us; speedup 1.0000x reference)
//
#include <hip/hip_runtime.h>

#define N_NODES 50000
#define N_PAD   50048                            // 782 * 64
#define N_EDGES 1600000
#define HD 128                                   // H*D = 8*16
#define CHUNK 4096
#define NCHUNK ((N_EDGES + CHUNK - 1) / CHUNK)   // 391
#define NBUCKET ((N_NODES + 127) / 128)          // 391 buckets of 128 nodes
#define PROJ_BLOCKS (N_PAD / 64)                 // 782

typedef __attribute__((ext_vector_type(8))) short short8;   // 8 bf16
typedef __attribute__((ext_vector_type(4))) float floatx4;

union U4S8 { uint4 u; short8 s; };

// round-to-nearest-even float -> bf16 bits
__device__ __forceinline__ unsigned short f2bf(float f) {
    unsigned u = __float_as_uint(f);
    unsigned r = (u + 0x7fffu + ((u >> 16) & 1u)) >> 16;
    return (unsigned short)r;
}

// ================= chunkhist + W-prep (fused grid) ==========================
// blocks [0,NCHUNK): per-chunk histogram of dst>>7 + btot atomics.
// blocks [NCHUNK,NCHUNK+24): W -> MFMA-fragment-order bf16 Wf.
__global__ __launch_bounds__(256) void k_chunkhist(
    const int* __restrict__ dst, int* __restrict__ chunkhist, int* __restrict__ btot,
    const float* __restrict__ WQ, const float* __restrict__ WK, const float* __restrict__ WV,
    unsigned short* __restrict__ Wf) {
    int t = threadIdx.x, c = blockIdx.x;
    if (c >= NCHUNK) {
        int tid = (c - NCHUNK) * 256 + t;        // 0..6143
        int lane = tid & 63;
        int kstep = (tid >> 6) & 3;
        int ntile = tid >> 8;
        int g = ntile >> 3;
        int col = (ntile & 7) * 16 + (lane & 15);
        int k0 = kstep * 32 + (lane >> 4) * 8;
        const float* W = (g == 0) ? WQ : (g == 1) ? WK : WV;
        unsigned short r[8];
#pragma unroll
        for (int j = 0; j < 8; ++j)
            r[j] = f2bf(W[(size_t)(k0 + j) * HD + col]);
        *(uint4*)(Wf + (size_t)tid * 8) = *(uint4*)r;
        return;
    }
    __shared__ int hist[NBUCKET];
    for (int i = t; i < NBUCKET; i += 256) hist[i] = 0;
    __syncthreads();
    int e0 = c * CHUNK;
    int cnt = min(CHUNK, N_EDGES - e0);
    const uint4* d4 = (const uint4*)(dst + e0);
    int cnt4 = cnt >> 2;
    for (int i = t; i < cnt4; i += 256) {
        uint4 v = d4[i];
        atomicAdd(&hist[v.x >> 7], 1);
        atomicAdd(&hist[v.y >> 7], 1);
        atomicAdd(&hist[v.z >> 7], 1);
        atomicAdd(&hist[v.w >> 7], 1);
    }
    __syncthreads();
    for (int i = t; i < NBUCKET; i += 256) {
        int v = hist[i];
        chunkhist[c * NBUCKET + i] = v;
        if (v) atomicAdd(&btot[i], v);           // fire-and-forget
    }
}

// per-(chunk,bucket) offsets; bucket base computed in-block (fused scan)
__global__ __launch_bounds__(256) void k_choff(const int* __restrict__ chunkhist,
                                               const int* __restrict__ btot,
                                               int* __restrict__ bucket_ptr,
                                               int* __restrict__ chunkoff) {
    int b = blockIdx.x, t = threadIdx.x;
    int x = 0;
    for (int i = t; i < NBUCKET; i += 256)
        if (i < b) x += btot[i];
    __shared__ int red[256];
    red[t] = x;
    __syncthreads();
    for (int off = 128; off > 0; off >>= 1) {
        if (t < off) red[t] += red[t + off];
        __syncthreads();
    }
    int base = red[0];
    if (t == 0) {
        bucket_ptr[b] = base;
        if (b == NBUCKET - 1) bucket_ptr[NBUCKET] = base + btot[b];
    }
    const int PER = (NCHUNK + 255) / 256;        // 2
    int c0 = t * PER;
    int v[PER];
    int s = 0;
#pragma unroll
    for (int i = 0; i < PER; ++i) {
        int c = c0 + i;
        v[i] = (c < NCHUNK) ? chunkhist[c * NBUCKET + b] : 0;
        s += v[i];
    }
    __shared__ int part[256];
    part[t] = s;
    __syncthreads();
    for (int off = 1; off < 256; off <<= 1) {
        int y = (t >= off) ? part[t - off] : 0;
        __syncthreads();
        part[t] += y;
        __syncthreads();
    }
    int run = base + part[t] - s;
#pragma unroll
    for (int i = 0; i < PER; ++i) {
        int c = c0 + i;
        if (c < NCHUNK) { chunkoff[c * NBUCKET + b] = run; run += v[i]; }
    }
}

// ================= scatter + proj (fused grid) ==============================
// blocks [0,NCHUNK): scatter edges into bucket-grouped 'packed'.
// blocks [NCHUNK,NCHUNK+PROJ_BLOCKS): bf16 MFMA projection (needs only Wf,
// produced by k_chunkhist; independent of edge preprocessing) — overlaps
// proj's ~77MB of streaming with scatter instead of serializing it.
__global__ __launch_bounds__(256) void k_scatter_proj(
    const int* __restrict__ src, const int* __restrict__ dst,
    const int* __restrict__ chunkoff, int* __restrict__ packed,
    const float* __restrict__ h, const unsigned short* __restrict__ Wf,
    const float* __restrict__ bQ, const float* __restrict__ bK, const float* __restrict__ bV,
    float* __restrict__ Qo, unsigned short* __restrict__ Kb, unsigned short* __restrict__ Vb) {
    int c = blockIdx.x;
    int t = threadIdx.x;
    if (c >= NCHUNK) {
        // ---- proj path: wave owns 16 rows, loops all 24 ntiles ----
        int blk = c - NCHUNK;
        int w = t >> 6;          // wave 0..3
        int l = t & 63;          // lane
        int row0 = blk * 64 + w * 16;
        int arow = row0 + (l & 15);
        int akoff = (l >> 4) * 8;
        bool rowok = arow < N_NODES;

        short8 a[4];
#pragma unroll
        for (int ks = 0; ks < 4; ++ks) {
            unsigned short r[8];
            if (rowok) {
                const float4* ap = (const float4*)(h + (size_t)arow * HD + ks * 32 + akoff);
                float4 f0 = ap[0], f1 = ap[1];
                r[0] = f2bf(f0.x); r[1] = f2bf(f0.y); r[2] = f2bf(f0.z); r[3] = f2bf(f0.w);
                r[4] = f2bf(f1.x); r[5] = f2bf(f1.y); r[6] = f2bf(f1.z); r[7] = f2bf(f1.w);
            } else {
#pragma unroll
                for (int j = 0; j < 8; ++j) r[j] = 0;
            }
            a[ks] = *(short8*)r;
        }

        int orow0 = row0 + (l >> 4) * 4;   // output rows orow0..orow0+3
#pragma unroll
        for (int nt = 0; nt < 24; ++nt) {
            floatx4 acc = (floatx4){0.f, 0.f, 0.f, 0.f};
#pragma unroll
            for (int ks = 0; ks < 4; ++ks) {
                U4S8 u;
                u.u = *(const uint4*)(Wf + ((size_t)(nt * 4 + ks) * 64 + l) * 8);
                acc = __builtin_amdgcn_mfma_f32_16x16x32_bf16(a[ks], u.s, acc, 0, 0, 0);
            }
            int g = nt >> 3;
            int cc = (nt & 7) * 16 + (l & 15);
            float bias = (g == 0) ? bQ[cc] : (g == 1) ? bK[cc] : bV[cc];
#pragma unroll
            for (int r = 0; r < 4; ++r) {
                int grow = orow0 + r;
                if (grow < N_NODES) {
                    float val = acc[r] + bias;
                    if (g == 0)      Qo[(size_t)grow * HD + cc] = val;
                    else if (g == 1) Kb[(size_t)grow * HD + cc] = f2bf(val);
                    else             Vb[(size_t)grow * HD + cc] = f2bf(val);
                }
            }
        }
        return;
    }
    // ---- scatter path ----
    __shared__ int cur[NBUCKET];
    for (int i = t; i < NBUCKET; i += 256) cur[i] = chunkoff[c * NBUCKET + i];
    __syncthreads();
    int e0 = c * CHUNK;
    int cnt = min(CHUNK, N_EDGES - e0);
    const uint4* d4 = (const uint4*)(dst + e0);
    const uint4* s4 = (const uint4*)(src + e0);
    int cnt4 = cnt >> 2;
    for (int i = t; i < cnt4; i += 256) {
        uint4 d = d4[i];
        uint4 s = s4[i];
        int pos;
        pos = atomicAdd(&cur[d.x >> 7], 1); packed[pos] = (s.x << 7) | (d.x & 127);
        pos = atomicAdd(&cur[d.y >> 7], 1); packed[pos] = (s.y << 7) | (d.y & 127);
        pos = atomicAdd(&cur[d.z >> 7], 1); packed[pos] = (s.z << 7) | (d.z & 127);
        pos = atomicAdd(&cur[d.w >> 7], 1); packed[pos] = (s.w << 7) | (d.w & 127);
    }
}

__global__ __launch_bounds__(256) void k_finalize(const int* __restrict__ bucket_ptr,
                                                  const int* __restrict__ packed,
                                                  int* __restrict__ row_ptr,
                                                  int* __restrict__ col_src) {
    __shared__ int hist[128], part[128], cur[128];
    int b = blockIdx.x, t = threadIdx.x;
    if (t < 128) hist[t] = 0;
    __syncthreads();
    int ebeg = bucket_ptr[b], eend = bucket_ptr[b + 1];
    int m = eend - ebeg;
    for (int i = t; i < m; i += 256)
        atomicAdd(&hist[packed[ebeg + i] & 127], 1);
    __syncthreads();
    int v = 0;
    if (t < 128) { v = hist[t]; part[t] = v; }
    __syncthreads();
    for (int off = 1; off < 128; off <<= 1) {
        int x = 0;
        if (t < 128 && t >= off) x = part[t - off];
        __syncthreads();
        if (t < 128) part[t] += x;
        __syncthreads();
    }
    if (t < 128) {
        int excl = part[t] - v;
        int node = b * 128 + t;
        if (node < N_NODES) row_ptr[node] = ebeg + excl;
        if (node == N_NODES - 1) row_ptr[N_NODES] = eend;
        cur[t] = ebeg + excl;
    }
    __syncthreads();
    for (int i = t; i < m; i += 256) {
        int p = packed[ebeg + i];
        int pos = atomicAdd(&cur[p & 127], 1);
        col_src[pos] = p >> 7;
    }
}

// ================= attention: 4 nodes/block, 16 edges/step ping-pong ========
// Gather-latency-bound: per step each lane keeps 8 gather instrs in flight
// (2x the old 1-deep/8-edge schedule) with zero register-rotation movs
// (manual unroll-by-2 ping-pong instead of cur=next copies). Loads exactly
// guarded by slot<mm (no wasted tail gathers); V regs zeroed in the masked
// path so sc=0 never multiplies Inf/NaN garbage.

__device__ __forceinline__ float blo(unsigned u) { return __uint_as_float(u << 16); }
__device__ __forceinline__ float bhi(unsigned u) { return __uint_as_float(u & 0xffff0000u); }

// load one edge's K/V half-rows for head p, guarded by slot<mm
#define LOADE(slot, K0, K1, V0, V1)                                           \
    {                                                                         \
        int _s = __shfl(e_l, (slot));                                         \
        if ((slot) < mm) {                                                    \
            const uint4* _Kp = (const uint4*)(Kb + (size_t)_s * HD + p * 16); \
            const uint4* _Vp = (const uint4*)(Vb + (size_t)_s * HD + p * 16); \
            K0 = _Kp[0]; K1 = _Kp[1]; V0 = _Vp[0]; V1 = _Vp[1];               \
        } else {                                                              \
            K0 = Z; K1 = Z; V0 = Z; V1 = Z;                                   \
        }                                                                     \
    }

#define EDGE(KA, KB, VA, VB, slot)                                            \
    {                                                                         \
        float dot = blo(KA.x) * q0.x + bhi(KA.x) * q0.y                       \
                  + blo(KA.y) * q0.z + bhi(KA.y) * q0.w                       \
                  + blo(KA.z) * q1.x + bhi(KA.z) * q1.y                       \
                  + blo(KA.w) * q1.z + bhi(KA.w) * q1.w                       \
                  + blo(KB.x) * q2.x + bhi(KB.x) * q2.y                       \
                  + blo(KB.y) * q2.z + bhi(KB.y) * q2.w                       \
                  + blo(KB.z) * q3.x + bhi(KB.z) * q3.y                       \
                  + blo(KB.w) * q3.z + bhi(KB.w) * q3.w;                      \
        float sc = __expf(fminf(fmaxf(dot * 0.25f, -5.f), 5.f));              \
        if ((slot) >= mm) sc = 0.f;                                           \
        acc[0]  = fmaf(sc, blo(VA.x), acc[0]);                                \
        acc[1]  = fmaf(sc, bhi(VA.x), acc[1]);                                \
        acc[2]  = fmaf(sc, blo(VA.y), acc[2]);                                \
        acc[3]  = fmaf(sc, bhi(VA.y), acc[3]);                                \
        acc[4]  = fmaf(sc, blo(VA.z), acc[4]);                                \
        acc[5]  = fmaf(sc, bhi(VA.z), acc[5]);                                \
        acc[6]  = fmaf(sc, blo(VA.w), acc[6]);                                \
        acc[7]  = fmaf(sc, bhi(VA.w), acc[7]);                                \
        acc[8]  = fmaf(sc, blo(VB.x), acc[8]);                                \
        acc[9]  = fmaf(sc, bhi(VB.x), acc[9]);                                \
        acc[10] = fmaf(sc, blo(VB.y), acc[10]);                               \
        acc[11] = fmaf(sc, bhi(VB.y), acc[11]);                               \
        acc[12] = fmaf(sc, blo(VB.z), acc[12]);                               \
        acc[13] = fmaf(sc, bhi(VB.z), acc[13]);                               \
        acc[14] = fmaf(sc, blo(VB.w), acc[14]);                               \
        acc[15] = fmaf(sc, bhi(VB.w), acc[15]);                               \
        z += sc;                                                              \
    }

__global__ __launch_bounds__(256, 4) void attn_kernel(
    const float* __restrict__ Q,
    const unsigned short* __restrict__ Kb, const unsigned short* __restrict__ Vb,
    const int* __restrict__ row_ptr, const int* __restrict__ col_src,
    float* __restrict__ out) {
    int n = blockIdx.x * 4 + (threadIdx.x >> 6);
    if (n >= N_NODES) return;
    int l = threadIdx.x & 63;
    int o = l >> 3;          // octet 0..7 (edge slot within 8)
    int p = l & 7;           // head index

    const float4* Qv = (const float4*)(Q + (size_t)n * HD + p * 16);
    float4 q0 = Qv[0], q1 = Qv[1], q2 = Qv[2], q3 = Qv[3];

    float acc[16];
#pragma unroll
    for (int j = 0; j < 16; ++j) acc[j] = 0.f;
    float z = 0.f;

    int beg = row_ptr[n], end = row_ptr[n + 1];
    const uint4 Z = {0u, 0u, 0u, 0u};

    for (int base = beg; base < end; base += 64) {
        int mm = min(64, end - base);
        int e_l = col_src[(base + l < end) ? (base + l) : beg];
        int steps = (mm + 15) >> 4;              // 16 edges per step

        uint4 kA0, kA1, vA0, vA1, kB0, kB1, vB0, vB1;   // ping: edges 16i+o, 16i+8+o
        uint4 kC0, kC1, vC0, vC1, kD0, kD1, vD0, vD1;   // pong

        LOADE(o, kA0, kA1, vA0, vA1);
        LOADE(8 + o, kB0, kB1, vB0, vB1);

        int i = 0;
        while (true) {
            bool has1 = (i + 1 < steps);
            if (has1) {
                int b1 = 16 * (i + 1);
                LOADE(b1 + o, kC0, kC1, vC0, vC1);
                LOADE(b1 + 8 + o, kD0, kD1, vD0, vD1);
            }
            int b0 = 16 * i;
            EDGE(kA0, kA1, vA0, vA1, b0 + o);
            EDGE(kB0, kB1, vB0, vB1, b0 + 8 + o);
            if (!has1) break;
            if (i + 2 < steps) {
                int b2 = 16 * (i + 2);
                LOADE(b2 + o, kA0, kA1, vA0, vA1);
                LOADE(b2 + 8 + o, kB0, kB1, vB0, vB1);
            }
            int b1 = 16 * (i + 1);
            EDGE(kC0, kC1, vC0, vC1, b1 + o);
            EDGE(kD0, kD1, vD0, vD1, b1 + 8 + o);
            i += 2;
            if (i >= steps) break;
        }
    }

#pragma unroll
    for (int j = 0; j < 16; ++j) {
        acc[j] += __shfl_xor(acc[j], 8);
        acc[j] += __shfl_xor(acc[j], 16);
        acc[j] += __shfl_xor(acc[j], 32);
    }
    z += __shfl_xor(z, 8);
    z += __shfl_xor(z, 16);
    z += __shfl_xor(z, 32);

    if (o == 0) {
        float inv = 1.f / z;
        float4* O = (float4*)(out + (size_t)n * HD + p * 16);
        O[0] = (float4){acc[0] * inv,  acc[1] * inv,  acc[2] * inv,  acc[3] * inv};
        O[1] = (float4){acc[4] * inv,  acc[5] * inv,  acc[6] * inv,  acc[7] * inv};
        O[2] = (float4){acc[8] * inv,  acc[9] * inv,  acc[10] * inv, acc[11] * inv};
        O[3] = (float4){acc[12] * inv, acc[13] * inv, acc[14] * inv, acc[15] * inv};
    }
}

// ================= launch ===================================================

static inline char* align256(char* p) {
    return (char*)(((uintptr_t)p + 255) & ~(uintptr_t)255);
}

extern "C" void kernel_launch(void* const* d_in, const int* in_sizes, int n_in,
                              void* d_out, int out_size, void* d_ws, size_t ws_size,
                              hipStream_t stream) {
    const float* h  = (const float*)d_in[0];
    const int*   src = (const int*)d_in[1];
    const int*   dst = (const int*)d_in[2];
    const float* WQ = (const float*)d_in[3];
    const float* WK = (const float*)d_in[4];
    const float* WV = (const float*)d_in[5];
    const float* bQ = (const float*)d_in[6];
    const float* bK = (const float*)d_in[7];
    const float* bV = (const float*)d_in[8];
    float* out = (float*)d_out;

    char* p = (char*)d_ws;
    float* Q = (float*)p;                    p += (size_t)N_PAD * HD * 4;
    unsigned short* Kb = (unsigned short*)p; p += (size_t)N_PAD * HD * 2;
    unsigned short* Vb = (unsigned short*)p; p += (size_t)N_PAD * HD * 2;
    unsigned short* Wf = (unsigned short*)p; p += (size_t)24 * 4 * 64 * 8 * 2;
    p = align256(p);
    int* row_ptr    = (int*)p;               p += (N_NODES + 2) * 4;
    p = align256(p);
    int* bucket_ptr = (int*)p;               p += (NBUCKET + 1) * 4;
    p = align256(p);
    int* btot       = (int*)p;               p += NBUCKET * 4;
    p = align256(p);
    int* chunkhist  = (int*)p;               p += (size_t)NCHUNK * NBUCKET * 4;
    p = align256(p);
    int* chunkoff   = (int*)p;               p += (size_t)NCHUNK * NBUCKET * 4;
    p = align256(p);
    int* packed     = (int*)p;               p += (size_t)N_EDGES * 4;
    p = align256(p);
    int* col_src    = (int*)p;               p += (size_t)N_EDGES * 4;

    (void)hipMemsetAsync(btot, 0, NBUCKET * sizeof(int), stream);
    k_chunkhist<<<NCHUNK + 24, 256, 0, stream>>>(dst, chunkhist, btot, WQ, WK, WV, Wf);
    k_choff<<<NBUCKET, 256, 0, stream>>>(chunkhist, btot, bucket_ptr, chunkoff);
    k_scatter_proj<<<NCHUNK + PROJ_BLOCKS, 256, 0, stream>>>(
        src, dst, chunkoff, packed, h, Wf, bQ, bK, bV, Q, Kb, Vb);
    k_finalize<<<NBUCKET, 256, 0, stream>>>(bucket_ptr, packed, row_ptr, col_src);
    attn_kernel<<<(N_NODES + 3) / 4, 256, 0, stream>>>(Q, Kb, Vb, row_ptr, col_src, out);
}

// Round 2
// 264.163 us; speedup vs baseline: 1.2501x; 1.2501x over previous
//
#include <hip/hip_runtime.h>

#define N_NODES 50000
#define N_PAD   50048                            // 782 * 64
#define N_EDGES 1600000
#define HD 128                                   // H*D = 8*16
#define CHUNK 4096
#define NCHUNK ((N_EDGES + CHUNK - 1) / CHUNK)   // 391
#define NBUCKET ((N_NODES + 127) / 128)          // 391 buckets of 128 nodes
#define PROJ_BLOCKS (N_PAD / 64)                 // 782

typedef __attribute__((ext_vector_type(8))) short short8;   // 8 bf16
typedef __attribute__((ext_vector_type(4))) float floatx4;

union U4S8 { uint4 u; short8 s; };

// round-to-nearest-even float -> bf16 bits
__device__ __forceinline__ unsigned short f2bf(float f) {
    unsigned u = __float_as_uint(f);
    unsigned r = (u + 0x7fffu + ((u >> 16) & 1u)) >> 16;
    return (unsigned short)r;
}

// ================= chunkhist + W-prep (fused grid) ==========================
// blocks [0,NCHUNK): per-chunk histogram of dst>>7 + btot atomics.
// blocks [NCHUNK,NCHUNK+24): W -> MFMA-fragment-order bf16 Wf.
__global__ __launch_bounds__(256) void k_chunkhist(
    const int* __restrict__ dst, int* __restrict__ chunkhist, int* __restrict__ btot,
    const float* __restrict__ WQ, const float* __restrict__ WK, const float* __restrict__ WV,
    unsigned short* __restrict__ Wf) {
    int t = threadIdx.x, c = blockIdx.x;
    if (c >= NCHUNK) {
        int tid = (c - NCHUNK) * 256 + t;        // 0..6143
        int lane = tid & 63;
        int kstep = (tid >> 6) & 3;
        int ntile = tid >> 8;
        int g = ntile >> 3;
        int col = (ntile & 7) * 16 + (lane & 15);
        int k0 = kstep * 32 + (lane >> 4) * 8;
        const float* W = (g == 0) ? WQ : (g == 1) ? WK : WV;
        unsigned short r[8];
#pragma unroll
        for (int j = 0; j < 8; ++j)
            r[j] = f2bf(W[(size_t)(k0 + j) * HD + col]);
        *(uint4*)(Wf + (size_t)tid * 8) = *(uint4*)r;
        return;
    }
    __shared__ int hist[NBUCKET];
    for (int i = t; i < NBUCKET; i += 256) hist[i] = 0;
    __syncthreads();
    int e0 = c * CHUNK;
    int cnt = min(CHUNK, N_EDGES - e0);
    const uint4* d4 = (const uint4*)(dst + e0);
    int cnt4 = cnt >> 2;
    for (int i = t; i < cnt4; i += 256) {
        uint4 v = d4[i];
        atomicAdd(&hist[v.x >> 7], 1);
        atomicAdd(&hist[v.y >> 7], 1);
        atomicAdd(&hist[v.z >> 7], 1);
        atomicAdd(&hist[v.w >> 7], 1);
    }
    __syncthreads();
    for (int i = t; i < NBUCKET; i += 256) {
        int v = hist[i];
        chunkhist[c * NBUCKET + i] = v;
        if (v) atomicAdd(&btot[i], v);           // fire-and-forget
    }
}

// per-(chunk,bucket) offsets; bucket base computed in-block (fused scan)
__global__ __launch_bounds__(256) void k_choff(const int* __restrict__ chunkhist,
                                               const int* __restrict__ btot,
                                               int* __restrict__ bucket_ptr,
                                               int* __restrict__ chunkoff) {
    int b = blockIdx.x, t = threadIdx.x;
    int x = 0;
    for (int i = t; i < NBUCKET; i += 256)
        if (i < b) x += btot[i];
    __shared__ int red[256];
    red[t] = x;
    __syncthreads();
    for (int off = 128; off > 0; off >>= 1) {
        if (t < off) red[t] += red[t + off];
        __syncthreads();
    }
    int base = red[0];
    if (t == 0) {
        bucket_ptr[b] = base;
        if (b == NBUCKET - 1) bucket_ptr[NBUCKET] = base + btot[b];
    }
    const int PER = (NCHUNK + 255) / 256;        // 2
    int c0 = t * PER;
    int v[PER];
    int s = 0;
#pragma unroll
    for (int i = 0; i < PER; ++i) {
        int c = c0 + i;
        v[i] = (c < NCHUNK) ? chunkhist[c * NBUCKET + b] : 0;
        s += v[i];
    }
    __shared__ int part[256];
    part[t] = s;
    __syncthreads();
    for (int off = 1; off < 256; off <<= 1) {
        int y = (t >= off) ? part[t - off] : 0;
        __syncthreads();
        part[t] += y;
        __syncthreads();
    }
    int run = base + part[t] - s;
#pragma unroll
    for (int i = 0; i < PER; ++i) {
        int c = c0 + i;
        if (c < NCHUNK) { chunkoff[c * NBUCKET + b] = run; run += v[i]; }
    }
}

// ================= scatter + proj (fused grid) ==============================
// blocks [0,NCHUNK): scatter edges into bucket-grouped 'packed'.
// blocks [NCHUNK,NCHUNK+PROJ_BLOCKS): bf16 MFMA projection (needs only Wf,
// produced by k_chunkhist; independent of edge preprocessing) — overlaps
// proj's ~77MB of streaming with scatter instead of serializing it.
__global__ __launch_bounds__(256) void k_scatter_proj(
    const int* __restrict__ src, const int* __restrict__ dst,
    const int* __restrict__ chunkoff, int* __restrict__ packed,
    const float* __restrict__ h, const unsigned short* __restrict__ Wf,
    const float* __restrict__ bQ, const float* __restrict__ bK, const float* __restrict__ bV,
    float* __restrict__ Qo, unsigned short* __restrict__ Kb, unsigned short* __restrict__ Vb) {
    int c = blockIdx.x;
    int t = threadIdx.x;
    if (c >= NCHUNK) {
        // ---- proj path: wave owns 16 rows, loops all 24 ntiles ----
        int blk = c - NCHUNK;
        int w = t >> 6;          // wave 0..3
        int l = t & 63;          // lane
        int row0 = blk * 64 + w * 16;
        int arow = row0 + (l & 15);
        int akoff = (l >> 4) * 8;
        bool rowok = arow < N_NODES;

        short8 a[4];
#pragma unroll
        for (int ks = 0; ks < 4; ++ks) {
            unsigned short r[8];
            if (rowok) {
                const float4* ap = (const float4*)(h + (size_t)arow * HD + ks * 32 + akoff);
                float4 f0 = ap[0], f1 = ap[1];
                r[0] = f2bf(f0.x); r[1] = f2bf(f0.y); r[2] = f2bf(f0.z); r[3] = f2bf(f0.w);
                r[4] = f2bf(f1.x); r[5] = f2bf(f1.y); r[6] = f2bf(f1.z); r[7] = f2bf(f1.w);
            } else {
#pragma unroll
                for (int j = 0; j < 8; ++j) r[j] = 0;
            }
            a[ks] = *(short8*)r;
        }

        int orow0 = row0 + (l >> 4) * 4;   // output rows orow0..orow0+3
#pragma unroll
        for (int nt = 0; nt < 24; ++nt) {
            floatx4 acc = (floatx4){0.f, 0.f, 0.f, 0.f};
#pragma unroll
            for (int ks = 0; ks < 4; ++ks) {
                U4S8 u;
                u.u = *(const uint4*)(Wf + ((size_t)(nt * 4 + ks) * 64 + l) * 8);
                acc = __builtin_amdgcn_mfma_f32_16x16x32_bf16(a[ks], u.s, acc, 0, 0, 0);
            }
            int g = nt >> 3;
            int cc = (nt & 7) * 16 + (l & 15);
            float bias = (g == 0) ? bQ[cc] : (g == 1) ? bK[cc] : bV[cc];
#pragma unroll
            for (int r = 0; r < 4; ++r) {
                int grow = orow0 + r;
                if (grow < N_NODES) {
                    float val = acc[r] + bias;
                    if (g == 0)      Qo[(size_t)grow * HD + cc] = val;
                    else if (g == 1) Kb[(size_t)grow * HD + cc] = f2bf(val);
                    else             Vb[(size_t)grow * HD + cc] = f2bf(val);
                }
            }
        }
        return;
    }
    // ---- scatter path ----
    __shared__ int cur[NBUCKET];
    for (int i = t; i < NBUCKET; i += 256) cur[i] = chunkoff[c * NBUCKET + i];
    __syncthreads();
    int e0 = c * CHUNK;
    int cnt = min(CHUNK, N_EDGES - e0);
    const uint4* d4 = (const uint4*)(dst + e0);
    const uint4* s4 = (const uint4*)(src + e0);
    int cnt4 = cnt >> 2;
    for (int i = t; i < cnt4; i += 256) {
        uint4 d = d4[i];
        uint4 s = s4[i];
        int pos;
        pos = atomicAdd(&cur[d.x >> 7], 1); packed[pos] = (s.x << 7) | (d.x & 127);
        pos = atomicAdd(&cur[d.y >> 7], 1); packed[pos] = (s.y << 7) | (d.y & 127);
        pos = atomicAdd(&cur[d.z >> 7], 1); packed[pos] = (s.z << 7) | (d.z & 127);
        pos = atomicAdd(&cur[d.w >> 7], 1); packed[pos] = (s.w << 7) | (d.w & 127);
    }
}

__global__ __launch_bounds__(256) void k_finalize(const int* __restrict__ bucket_ptr,
                                                  const int* __restrict__ packed,
                                                  int* __restrict__ row_ptr,
                                                  int* __restrict__ col_src) {
    __shared__ int hist[128], part[128], cur[128];
    int b = blockIdx.x, t = threadIdx.x;
    if (t < 128) hist[t] = 0;
    __syncthreads();
    int ebeg = bucket_ptr[b], eend = bucket_ptr[b + 1];
    int m = eend - ebeg;
    for (int i = t; i < m; i += 256)
        atomicAdd(&hist[packed[ebeg + i] & 127], 1);
    __syncthreads();
    int v = 0;
    if (t < 128) { v = hist[t]; part[t] = v; }
    __syncthreads();
    for (int off = 1; off < 128; off <<= 1) {
        int x = 0;
        if (t < 128 && t >= off) x = part[t - off];
        __syncthreads();
        if (t < 128) part[t] += x;
        __syncthreads();
    }
    if (t < 128) {
        int excl = part[t] - v;
        int node = b * 128 + t;
        if (node < N_NODES) row_ptr[node] = ebeg + excl;
        if (node == N_NODES - 1) row_ptr[N_NODES] = eend;
        cur[t] = ebeg + excl;
    }
    __syncthreads();
    for (int i = t; i < m; i += 256) {
        int p = packed[ebeg + i];
        int pos = atomicAdd(&cur[p & 127], 1);
        col_src[pos] = p >> 7;
    }
}

// ================= attention: 4 nodes/block, node-range split ===============
// Round-0 proven structure: depth-1 rotating prefetch, UNCONDITIONAL loads
// (e_l clamped so every address is valid; masking happens on the score),
// uniform prefetch guard (i+1<steps is wave-uniform). No divergent load
// guards, no ping-pong register explosion -> no spills.

__device__ __forceinline__ float blo(unsigned u) { return __uint_as_float(u << 16); }
__device__ __forceinline__ float bhi(unsigned u) { return __uint_as_float(u & 0xffff0000u); }

__global__ __launch_bounds__(256) void attn_kernel(
    const float* __restrict__ Q,
    const unsigned short* __restrict__ Kb, const unsigned short* __restrict__ Vb,
    const int* __restrict__ row_ptr, const int* __restrict__ col_src,
    float* __restrict__ out) {
    int n = blockIdx.x * 4 + (threadIdx.x >> 6);
    if (n >= N_NODES) return;
    int l = threadIdx.x & 63;
    int o = l >> 3;          // octet 0..7 (edge slot)
    int p = l & 7;           // head index

    const float4* Qv = (const float4*)(Q + (size_t)n * HD + p * 16);
    float4 q0 = Qv[0], q1 = Qv[1], q2 = Qv[2], q3 = Qv[3];

    float acc[16];
#pragma unroll
    for (int j = 0; j < 16; ++j) acc[j] = 0.f;
    float z = 0.f;

    int beg = row_ptr[n], end = row_ptr[n + 1];

    for (int base = beg; base < end; base += 64) {
        int mm = min(64, end - base);
        int e_l = col_src[(base + l < end) ? (base + l) : beg];
        int steps = (mm + 7) >> 3;

        int s0 = __shfl(e_l, o);
        const uint4* Kp = (const uint4*)(Kb + (size_t)s0 * HD + p * 16);
        const uint4* Vp = (const uint4*)(Vb + (size_t)s0 * HD + p * 16);
        uint4 ka = Kp[0], kb = Kp[1], va = Vp[0], vb = Vp[1];

        for (int i = 0; i < steps; ++i) {
            uint4 nka = ka, nkb = kb, nva = va, nvb = vb;
            if (i + 1 < steps) {
                int s1 = __shfl(e_l, 8 * (i + 1) + o);
                const uint4* Kn = (const uint4*)(Kb + (size_t)s1 * HD + p * 16);
                const uint4* Vn = (const uint4*)(Vb + (size_t)s1 * HD + p * 16);
                nka = Kn[0]; nkb = Kn[1]; nva = Vn[0]; nvb = Vn[1];
            }
            float dot = blo(ka.x) * q0.x + bhi(ka.x) * q0.y
                      + blo(ka.y) * q0.z + bhi(ka.y) * q0.w
                      + blo(ka.z) * q1.x + bhi(ka.z) * q1.y
                      + blo(ka.w) * q1.z + bhi(ka.w) * q1.w
                      + blo(kb.x) * q2.x + bhi(kb.x) * q2.y
                      + blo(kb.y) * q2.z + bhi(kb.y) * q2.w
                      + blo(kb.z) * q3.x + bhi(kb.z) * q3.y
                      + blo(kb.w) * q3.z + bhi(kb.w) * q3.w;
            float sc = __expf(fminf(fmaxf(dot * 0.25f, -5.f), 5.f));
            if (8 * i + o >= mm) sc = 0.f;
            acc[0]  = fmaf(sc, blo(va.x), acc[0]);
            acc[1]  = fmaf(sc, bhi(va.x), acc[1]);
            acc[2]  = fmaf(sc, blo(va.y), acc[2]);
            acc[3]  = fmaf(sc, bhi(va.y), acc[3]);
            acc[4]  = fmaf(sc, blo(va.z), acc[4]);
            acc[5]  = fmaf(sc, bhi(va.z), acc[5]);
            acc[6]  = fmaf(sc, blo(va.w), acc[6]);
            acc[7]  = fmaf(sc, bhi(va.w), acc[7]);
            acc[8]  = fmaf(sc, blo(vb.x), acc[8]);
            acc[9]  = fmaf(sc, bhi(vb.x), acc[9]);
            acc[10] = fmaf(sc, blo(vb.y), acc[10]);
            acc[11] = fmaf(sc, bhi(vb.y), acc[11]);
            acc[12] = fmaf(sc, blo(vb.z), acc[12]);
            acc[13] = fmaf(sc, bhi(vb.z), acc[13]);
            acc[14] = fmaf(sc, blo(vb.w), acc[14]);
            acc[15] = fmaf(sc, bhi(vb.w), acc[15]);
            z += sc;
            ka = nka; kb = nkb; va = nva; vb = nvb;
        }
    }

#pragma unroll
    for (int j = 0; j < 16; ++j) {
        acc[j] += __shfl_xor(acc[j], 8);
        acc[j] += __shfl_xor(acc[j], 16);
        acc[j] += __shfl_xor(acc[j], 32);
    }
    z += __shfl_xor(z, 8);
    z += __shfl_xor(z, 16);
    z += __shfl_xor(z, 32);

    if (o == 0) {
        float inv = 1.f / z;
        float4* O = (float4*)(out + (size_t)n * HD + p * 16);
        O[0] = (float4){acc[0] * inv,  acc[1] * inv,  acc[2] * inv,  acc[3] * inv};
        O[1] = (float4){acc[4] * inv,  acc[5] * inv,  acc[6] * inv,  acc[7] * inv};
        O[2] = (float4){acc[8] * inv,  acc[9] * inv,  acc[10] * inv, acc[11] * inv};
        O[3] = (float4){acc[12] * inv, acc[13] * inv, acc[14] * inv, acc[15] * inv};
    }
}

// ================= launch ===================================================

static inline char* align256(char* p) {
    return (char*)(((uintptr_t)p + 255) & ~(uintptr_t)255);
}

extern "C" void kernel_launch(void* const* d_in, const int* in_sizes, int n_in,
                              void* d_out, int out_size, void* d_ws, size_t ws_size,
                              hipStream_t stream) {
    const float* h  = (const float*)d_in[0];
    const int*   src = (const int*)d_in[1];
    const int*   dst = (const int*)d_in[2];
    const float* WQ = (const float*)d_in[3];
    const float* WK = (const float*)d_in[4];
    const float* WV = (const float*)d_in[5];
    const float* bQ = (const float*)d_in[6];
    const float* bK = (const float*)d_in[7];
    const float* bV = (const float*)d_in[8];
    float* out = (float*)d_out;

    char* p = (char*)d_ws;
    float* Q = (float*)p;                    p += (size_t)N_PAD * HD * 4;
    unsigned short* Kb = (unsigned short*)p; p += (size_t)N_PAD * HD * 2;
    unsigned short* Vb = (unsigned short*)p; p += (size_t)N_PAD * HD * 2;
    unsigned short* Wf = (unsigned short*)p; p += (size_t)24 * 4 * 64 * 8 * 2;
    p = align256(p);
    int* row_ptr    = (int*)p;               p += (N_NODES + 2) * 4;
    p = align256(p);
    int* bucket_ptr = (int*)p;               p += (NBUCKET + 1) * 4;
    p = align256(p);
    int* btot       = (int*)p;               p += NBUCKET * 4;
    p = align256(p);
    int* chunkhist  = (int*)p;               p += (size_t)NCHUNK * NBUCKET * 4;
    p = align256(p);
    int* chunkoff   = (int*)p;               p += (size_t)NCHUNK * NBUCKET * 4;
    p = align256(p);
    int* packed     = (int*)p;               p += (size_t)N_EDGES * 4;
    p = align256(p);
    int* col_src    = (int*)p;               p += (size_t)N_EDGES * 4;

    (void)hipMemsetAsync(btot, 0, NBUCKET * sizeof(int), stream);
    k_chunkhist<<<NCHUNK + 24, 256, 0, stream>>>(dst, chunkhist, btot, WQ, WK, WV, Wf);
    k_choff<<<NBUCKET, 256, 0, stream>>>(chunkhist, btot, bucket_ptr, chunkoff);
    k_scatter_proj<<<NCHUNK + PROJ_BLOCKS, 256, 0, stream>>>(
        src, dst, chunkoff, packed, h, Wf, bQ, bK, bV, Q, Kb, Vb);
    k_finalize<<<NBUCKET, 256, 0, stream>>>(bucket_ptr, packed, row_ptr, col_src);
    attn_kernel<<<(N_NODES + 3) / 4, 256, 0, stream>>>(Q, Kb, Vb, row_ptr, col_src, out);
}